// Round 1
// baseline (331.570 us; speedup 1.0000x reference)
//
#include <hip/hip_runtime.h>

#define SDIM 2048
#define NHEADS 16
#define HD 64

typedef __attribute__((ext_vector_type(8))) short bf16x8;
typedef __attribute__((ext_vector_type(8))) unsigned short u16x8;
typedef __attribute__((ext_vector_type(4))) float f32x4;
typedef unsigned short u16;

static __device__ __forceinline__ u16 f2bf(float f) {
  unsigned u = __builtin_bit_cast(unsigned, f);
  u += 0x7fffu + ((u >> 16) & 1u);   // RNE
  return (u16)(u >> 16);
}

static __device__ __forceinline__ f32x4 mfma16(bf16x8 a, bf16x8 b, f32x4 c) {
  return __builtin_amdgcn_mfma_f32_16x16x32_bf16(a, b, c, 0, 0, 0);
}

// ---------- prep: fp32 -> bf16, 8 elems/thread ----------
__global__ void cvt_kernel(const float* __restrict__ in, u16* __restrict__ out, int n8) {
  int i = blockIdx.x * blockDim.x + threadIdx.x;
  if (i >= n8) return;
  const float4* p = (const float4*)(in + (long)i * 8);
  float4 a = p[0], b = p[1];
  u16x8 r;
  r[0] = f2bf(a.x); r[1] = f2bf(a.y); r[2] = f2bf(a.z); r[3] = f2bf(a.w);
  r[4] = f2bf(b.x); r[5] = f2bf(b.y); r[6] = f2bf(b.z); r[7] = f2bf(b.w);
  *(u16x8*)(out + (long)i * 8) = r;
}

// ---------- prep: W [K][N] fp32 -> Wt [N][K] bf16 ----------
__global__ void transpose_cvt(const float* __restrict__ W, u16* __restrict__ Wt, int K, int N) {
  __shared__ float t[32][33];
  int tx = threadIdx.x & 31, ty = threadIdx.x >> 5;   // 32 x 8
  int n0 = blockIdx.x * 32, k0 = blockIdx.y * 32;
#pragma unroll
  for (int i = 0; i < 32; i += 8) t[ty + i][tx] = W[(long)(k0 + ty + i) * N + n0 + tx];
  __syncthreads();
#pragma unroll
  for (int i = 0; i < 32; i += 8) Wt[(long)(n0 + ty + i) * K + k0 + tx] = f2bf(t[tx][ty + i]);
}

// ---------- bf16 GEMM, 128x128x64 tile, 4 waves, each wave 64x64 ----------
// A [M][K] bf16 row-major, Bt [N][K] bf16 (i.e. B transposed), C = A*B + bias
// EPI==0: write fp32 Cf[M][N].  EPI==1: scatter qkv into Qb/Kb/Vtb (head-split).
template <int EPI>
__global__ __launch_bounds__(256) void gemm_bf16(
    const u16* __restrict__ A, const u16* __restrict__ Bt,
    const float* __restrict__ bias, float* __restrict__ Cf,
    u16* __restrict__ Qb, u16* __restrict__ Kb, u16* __restrict__ Vtb,
    int M, int N, int K)
{
  __shared__ __align__(16) u16 As[128][72];
  __shared__ __align__(16) u16 Bs[128][72];
  const int tid = threadIdx.x, lane = tid & 63, wid = tid >> 6;
  const int wm = wid >> 1, wn = wid & 1;
  const int l15 = lane & 15, l4 = lane >> 4;
  const int m0 = blockIdx.y * 128, n0 = blockIdx.x * 128;
  const int ro = (tid & 7) * 8;            // 8-elem chunk offset in a 64-elem row

  f32x4 acc[4][4];
#pragma unroll
  for (int i = 0; i < 4; ++i)
#pragma unroll
    for (int j = 0; j < 4; ++j) acc[i][j] = {0.f, 0.f, 0.f, 0.f};

  uint4 ar[4], br[4];
  auto issue = [&](int kc) {
#pragma unroll
    for (int i = 0; i < 4; ++i) {
      int r = (tid >> 3) + i * 32;
      ar[i] = *(const uint4*)(A  + (long)(m0 + r) * K + kc + ro);
      br[i] = *(const uint4*)(Bt + (long)(n0 + r) * K + kc + ro);
    }
  };
  auto commit = [&]() {
#pragma unroll
    for (int i = 0; i < 4; ++i) {
      int r = (tid >> 3) + i * 32;
      *(uint4*)&As[r][ro] = ar[i];
      *(uint4*)&Bs[r][ro] = br[i];
    }
  };

  issue(0);
  const int nk = K >> 6;
  for (int kt = 0; kt < nk; ++kt) {
    commit();
    __syncthreads();
    if (kt + 1 < nk) issue((kt + 1) << 6);   // overlap next-tile loads with compute
#pragma unroll
    for (int kk = 0; kk < 2; ++kk) {
      bf16x8 af[4], bfr[4];
#pragma unroll
      for (int mt = 0; mt < 4; ++mt)
        af[mt] = *(const bf16x8*)&As[wm * 64 + mt * 16 + l15][kk * 32 + l4 * 8];
#pragma unroll
      for (int nt = 0; nt < 4; ++nt)
        bfr[nt] = *(const bf16x8*)&Bs[wn * 64 + nt * 16 + l15][kk * 32 + l4 * 8];
#pragma unroll
      for (int mt = 0; mt < 4; ++mt)
#pragma unroll
        for (int nt = 0; nt < 4; ++nt)
          acc[mt][nt] = mfma16(af[mt], bfr[nt], acc[mt][nt]);
    }
    __syncthreads();
  }

#pragma unroll
  for (int mt = 0; mt < 4; ++mt)
#pragma unroll
    for (int nt = 0; nt < 4; ++nt)
#pragma unroll
      for (int r = 0; r < 4; ++r) {
        int row = m0 + wm * 64 + mt * 16 + l4 * 4 + r;
        int col = n0 + wn * 64 + nt * 16 + l15;
        float v = acc[mt][nt][r] + bias[col];
        if (EPI == 0) {
          Cf[(long)row * N + col] = v;
        } else {
          // qkv layout: col = h*192 + w2 ; w2: [0,64) Q, [64,128) K, [128,192) V
          int h = col / 192, w2 = col % 192;
          int b = row >> 11, s = row & 2047;
          int bh = b * NHEADS + h;
          u16 bv = f2bf(v);
          if (w2 < 64)        Qb[(long)(bh * SDIM + s) * HD + w2] = bv;
          else if (w2 < 128)  Kb[(long)(bh * SDIM + s) * HD + (w2 - 64)] = bv;
          else                Vtb[(long)(bh * HD + (w2 - 128)) * SDIM + s] = bv;
        }
      }
}

// ---------- flash attention: grid (S/128, B*H), 4 waves, QBLK=128, KBLK=64 ----------
__global__ __launch_bounds__(256) void attn_kernel(
    const u16* __restrict__ Qg, const u16* __restrict__ Kg,
    const u16* __restrict__ Vtg, const int* __restrict__ maskg,
    u16* __restrict__ Og)
{
  __shared__ __align__(16) u16 Ks[2][64][72];
  __shared__ __align__(16) u16 Vs[2][64][72];   // rows = d, cols = k
  __shared__ __align__(16) u16 Ps[128][80];
  const int tid = threadIdx.x, lane = tid & 63, w = tid >> 6;
  const int l15 = lane & 15, l4 = lane >> 4;
  const int bh = blockIdx.y, qt = blockIdx.x;
  const u16* Qp = Qg + ((long)bh * SDIM + qt * 128) * HD;
  const u16* Kp = Kg + (long)bh * SDIM * HD;
  const u16* Vp = Vtg + (long)bh * HD * SDIM;
  const int* mp = maskg + (bh >> 4) * SDIM;
  const int so = (tid & 7) * 8;

  // Q fragments straight from global (read once)
  bf16x8 qa[2][2];
#pragma unroll
  for (int rt = 0; rt < 2; ++rt)
#pragma unroll
    for (int ks = 0; ks < 2; ++ks)
      qa[rt][ks] = *(const bf16x8*)(Qp + (w * 32 + rt * 16 + l15) * HD + ks * 32 + l4 * 8);

  f32x4 O[2][4];
  float mrow[2][4], lrow[2][4];
#pragma unroll
  for (int rt = 0; rt < 2; ++rt) {
#pragma unroll
    for (int dt = 0; dt < 4; ++dt) O[rt][dt] = {0.f, 0.f, 0.f, 0.f};
#pragma unroll
    for (int r = 0; r < 4; ++r) { mrow[rt][r] = -1e30f; lrow[rt][r] = 0.f; }
  }

  uint4 kr[2], vr[2];
  auto issue = [&](int kt2) {
    int kb = kt2 * 64;
#pragma unroll
    for (int i = 0; i < 2; ++i) {
      int r = (tid >> 3) + i * 32;
      kr[i] = *(const uint4*)(Kp + (long)(kb + r) * HD + so);
      vr[i] = *(const uint4*)(Vp + (long)r * SDIM + kb + so);
    }
  };
  auto commit = [&](int buf) {
#pragma unroll
    for (int i = 0; i < 2; ++i) {
      int r = (tid >> 3) + i * 32;
      *(uint4*)&Ks[buf][r][so] = kr[i];
      *(uint4*)&Vs[buf][r][so] = vr[i];
    }
  };

  issue(0); commit(0);
  __syncthreads();

  for (int kt = 0; kt < SDIM / 64; ++kt) {
    const int cur = kt & 1;
    if (kt + 1 < SDIM / 64) issue(kt + 1);    // prefetch into regs, commit after compute
    float mb[4];
#pragma unroll
    for (int nt = 0; nt < 4; ++nt)
      mb[nt] = mp[kt * 64 + nt * 16 + l15] ? 0.f : -1e30f;

    // S = Q K^T (per wave: 32 x 64)
    f32x4 sc[2][4];
#pragma unroll
    for (int nt = 0; nt < 4; ++nt) {
      bf16x8 kb0 = *(const bf16x8*)&Ks[cur][nt * 16 + l15][l4 * 8];
      bf16x8 kb1 = *(const bf16x8*)&Ks[cur][nt * 16 + l15][32 + l4 * 8];
#pragma unroll
      for (int rt = 0; rt < 2; ++rt) {
        f32x4 z = {0.f, 0.f, 0.f, 0.f};
        z = mfma16(qa[rt][0], kb0, z);
        z = mfma16(qa[rt][1], kb1, z);
        sc[rt][nt] = z;
      }
    }

    // online softmax + P -> LDS (bf16)
#pragma unroll
    for (int rt = 0; rt < 2; ++rt) {
#pragma unroll
      for (int r = 0; r < 4; ++r) {
        float s0 = sc[rt][0][r] * 0.125f + mb[0];
        float s1 = sc[rt][1][r] * 0.125f + mb[1];
        float s2 = sc[rt][2][r] * 0.125f + mb[2];
        float s3 = sc[rt][3][r] * 0.125f + mb[3];
        float mx = fmaxf(fmaxf(s0, s1), fmaxf(s2, s3));
#pragma unroll
        for (int off = 1; off < 16; off <<= 1) mx = fmaxf(mx, __shfl_xor(mx, off));
        float mold = mrow[rt][r];
        float mn = fmaxf(mold, mx);
        float al = __expf(mold - mn);
        mrow[rt][r] = mn;
        float p0 = __expf(s0 - mn), p1 = __expf(s1 - mn);
        float p2 = __expf(s2 - mn), p3 = __expf(s3 - mn);
        float rs = p0 + p1 + p2 + p3;
#pragma unroll
        for (int off = 1; off < 16; off <<= 1) rs += __shfl_xor(rs, off);
        lrow[rt][r] = lrow[rt][r] * al + rs;
#pragma unroll
        for (int dt = 0; dt < 4; ++dt) O[rt][dt][r] *= al;
        int prow = w * 32 + rt * 16 + l4 * 4 + r;
        Ps[prow][0 + l15] = f2bf(p0);
        Ps[prow][16 + l15] = f2bf(p1);
        Ps[prow][32 + l15] = f2bf(p2);
        Ps[prow][48 + l15] = f2bf(p3);
      }
    }
    // P writes are consumed only by this same wave -> lgkmcnt(0) suffices (no barrier)
    asm volatile("s_waitcnt lgkmcnt(0)" ::: "memory");
    __builtin_amdgcn_sched_barrier(0);

    // O += P V   (P: 32 x 64, V: 64 x 64)
#pragma unroll
    for (int ks2 = 0; ks2 < 2; ++ks2) {
      bf16x8 pa[2];
#pragma unroll
      for (int rt = 0; rt < 2; ++rt)
        pa[rt] = *(const bf16x8*)&Ps[w * 32 + rt * 16 + l15][ks2 * 32 + l4 * 8];
#pragma unroll
      for (int dt = 0; dt < 4; ++dt) {
        bf16x8 vb = *(const bf16x8*)&Vs[cur][dt * 16 + l15][ks2 * 32 + l4 * 8];
#pragma unroll
        for (int rt = 0; rt < 2; ++rt) O[rt][dt] = mfma16(pa[rt], vb, O[rt][dt]);
      }
    }
    if (kt + 1 < SDIM / 64) commit(cur ^ 1);
    __syncthreads();   // the only barrier per k-tile (double-buffered K/V)
  }

  const int b = bh >> 4, h = bh & 15;
#pragma unroll
  for (int rt = 0; rt < 2; ++rt)
#pragma unroll
    for (int dt = 0; dt < 4; ++dt)
#pragma unroll
      for (int r = 0; r < 4; ++r) {
        int s = qt * 128 + w * 32 + rt * 16 + l4 * 4 + r;
        int d = dt * 16 + l15;
        float o = O[rt][dt][r] / lrow[rt][r];
        Og[((long)(b * SDIM + s)) * 1024 + h * HD + d] = f2bf(o);
      }
}

extern "C" void kernel_launch(void* const* d_in, const int* in_sizes, int n_in,
                              void* d_out, int out_size, void* d_ws, size_t ws_size,
                              hipStream_t stream) {
  const float* x    = (const float*)d_in[0];
  const int*   am   = (const int*)d_in[1];
  const float* Wqkv = (const float*)d_in[2];
  const float* bqkv = (const float*)d_in[3];
  const float* Wout = (const float*)d_in[4];
  const float* bout = (const float*)d_in[5];
  float* out = (float*)d_out;
  char* ws = (char*)d_ws;

  u16* xb  = (u16*)(ws);                              // 8 MB  x as bf16 [4096][1024]
  u16* wqt = (u16*)(ws + (size_t)8  * 1024 * 1024);   // 6 MB  W_qkv^T bf16 [3072][1024]
  u16* wot = (u16*)(ws + (size_t)14 * 1024 * 1024);   // 2 MB  W_out^T bf16 [1024][1024]
  u16* Qb  = (u16*)(ws + (size_t)16 * 1024 * 1024);   // 8 MB  Q [32][2048][64]
  u16* Kb  = (u16*)(ws + (size_t)24 * 1024 * 1024);   // 8 MB  K [32][2048][64]
  u16* Vtb = (u16*)(ws + (size_t)32 * 1024 * 1024);   // 8 MB  V^T [32][64][2048]
  u16* AOb = (u16*)(ws + (size_t)40 * 1024 * 1024);   // 8 MB  attn out bf16 [4096][1024]

  cvt_kernel<<<2048, 256, 0, stream>>>(x, xb, 524288);
  transpose_cvt<<<dim3(96, 32), 256, 0, stream>>>(Wqkv, wqt, 1024, 3072);
  transpose_cvt<<<dim3(32, 32), 256, 0, stream>>>(Wout, wot, 1024, 1024);
  gemm_bf16<1><<<dim3(24, 32), 256, 0, stream>>>(xb, wqt, bqkv, nullptr, Qb, Kb, Vtb,
                                                 4096, 3072, 1024);
  attn_kernel<<<dim3(16, 32), 256, 0, stream>>>(Qb, Kb, Vtb, am, AOb);
  gemm_bf16<0><<<dim3(8, 32), 256, 0, stream>>>(AOb, wot, bout, out, nullptr, nullptr, nullptr,
                                                4096, 1024, 1024);
}